// Round 7
// baseline (507.310 us; speedup 1.0000x reference)
//
#include <hip/hip_runtime.h>
#include <hip/hip_bf16.h>

typedef __attribute__((ext_vector_type(8))) short short8;
typedef __attribute__((ext_vector_type(4))) float floatx4;
typedef __attribute__((ext_vector_type(16))) float floatx16;

constexpr int B = 4, H = 16, S = 2048, D = 64;
constexpr int BM = 128;  // queries per workgroup (32 per wave, 4 waves)
constexpr int BN = 64;   // keys per main-loop iteration
constexpr int LDK = 72;  // ks row stride: 36 dwords/row -> +4 bank rotation/row

// fold softmax scale and log2(e) into Q: exp(x*0.125) == exp2(x*0.125*log2e)
#define QSCALE (0.125f * 1.44269504088896f)

// 8 contiguous fp32 -> 8 bf16 via packed converts
__device__ __forceinline__ short8 ld8f_bf(const float* p, float sc) {
  floatx4 a = *(const floatx4*)p;
  floatx4 b = *(const floatx4*)(p + 4);
  union { short8 s; __hip_bfloat162 h[4]; } u;
  u.h[0] = __float22bfloat162_rn(make_float2(a[0] * sc, a[1] * sc));
  u.h[1] = __float22bfloat162_rn(make_float2(a[2] * sc, a[3] * sc));
  u.h[2] = __float22bfloat162_rn(make_float2(b[0] * sc, b[1] * sc));
  u.h[3] = __float22bfloat162_rn(make_float2(b[2] * sc, b[3] * sc));
  return u.s;
}

__device__ __forceinline__ unsigned pk2(float lo, float hi) {
  __hip_bfloat162 h = __float22bfloat162_rn(make_float2(lo, hi));
  return *reinterpret_cast<unsigned*>(&h);
}

__global__ __launch_bounds__(256, 3)
void attn_flash_kernel(const float* __restrict__ Q, const float* __restrict__ Kp,
                       const float* __restrict__ Vp, const int* __restrict__ Mask,
                       float* __restrict__ Out) {
  // K [key][d] stride 72 (padded, uniform-minimum banks for row-varying b128).
  // V [d][sigma(key) ^ ((d&7)<<3)] where sigma swaps key bits 2<->3: makes the
  // PV B-frag slot order match the QK^T C-output order held in registers, so
  // P needs NO redistribution (no LDS round-trip, no permlane).
  __shared__ __align__(16) short ks[2][BN * LDK];
  __shared__ __align__(16) short vs[2][D * 64];
  __shared__ __align__(16) int ms[2][BN];

  const int t = threadIdx.x;
  const int wave = t >> 6;
  const int lane = t & 63;
  const int l5 = lane & 31;
  const int hi = lane >> 5;

  const int bh = blockIdx.y;
  const int bb = bh >> 4;
  const int mblk = blockIdx.x;

  const float* Qb = Q + (size_t)bh * S * D;
  const float* Kb = Kp + (size_t)bh * S * D;
  const float* Vb = Vp + (size_t)bh * S * D;
  const int* Mb = Mask + bb * S;

  // Q as MFMA B-operand (swapped QK^T): lane holds Q[q=l5][d=kd*16+hi*8+j]
  const int qrow = mblk * BM + wave * 32 + l5;
  const float* qp = Qb + (size_t)qrow * D;
  short8 qf[4];
#pragma unroll
  for (int kd = 0; kd < 4; ++kd)
    qf[kd] = ld8f_bf(qp + kd * 16 + hi * 8, QSCALE);

  // all-ones B fragment: l row-sums via the matrix pipe
  short8 ones;
#pragma unroll
  for (int j = 0; j < 8; ++j) ones[j] = (short)0x3F80;  // bf16 1.0

  floatx16 acc[2], accl;
#pragma unroll
  for (int d = 0; d < 2; ++d)
#pragma unroll
    for (int r = 0; r < 16; ++r) acc[d][r] = 0.f;
#pragma unroll
  for (int r = 0; r < 16; ++r) accl[r] = 0.f;

  // ---- staging geometry (unchanged from verified r6 except V position map) ----
  const int r0 = t >> 3;          // K row 0..31 (and +32)
  const int c0 = t & 7;
  const int r1 = r0 + 32;
  const int kp = t & 31;          // V key pair: keys 2kp, 2kp+1
  const int cv = t >> 5;          // V d-chunk 0..7
  const float* kg0 = Kb + (size_t)r0 * D + c0 * 8;
  const float* kg1 = Kb + (size_t)r1 * D + c0 * 8;
  const float* vg0 = Vb + (size_t)(2 * kp) * D + cv * 8;
  const float* vg1 = Vb + (size_t)(2 * kp + 1) * D + cv * 8;
  // sigma(2kp): swap bits 2 and 3 of the key index (bit 0 preserved -> the
  // pk2'd key-pair stays one aligned dword)
  const int k2 = 2 * kp;
  const int sk = (k2 & ~12) | ((k2 & 4) << 1) | ((k2 & 8) >> 1);

  floatx4 kr[2][2], vr[2][2];   // staged next-tile fp32 (issue-early, write-late)
  int mreg = 0;

  auto stage_load = [&](int kb) {   // T14: issue global loads early
    const size_t off = (size_t)kb * D;
    kr[0][0] = *(const floatx4*)(kg0 + off);
    kr[0][1] = *(const floatx4*)(kg0 + off + 4);
    kr[1][0] = *(const floatx4*)(kg1 + off);
    kr[1][1] = *(const floatx4*)(kg1 + off + 4);
    vr[0][0] = *(const floatx4*)(vg0 + off);
    vr[0][1] = *(const floatx4*)(vg0 + off + 4);
    vr[1][0] = *(const floatx4*)(vg1 + off);
    vr[1][1] = *(const floatx4*)(vg1 + off + 4);
    if (t < BN) mreg = Mb[kb + t];
  };

  auto stage_write = [&](int buf) {  // T14: convert + LDS write, late
    if (t < BN) ms[buf][t] = mreg;
#pragma unroll
    for (int it = 0; it < 2; ++it) {
      const int r = it ? r1 : r0;
      floatx4 a = kr[it][0], b = kr[it][1];
      union { short8 s; __hip_bfloat162 h[4]; } u;
      u.h[0] = __float22bfloat162_rn(make_float2(a[0], a[1]));
      u.h[1] = __float22bfloat162_rn(make_float2(a[2], a[3]));
      u.h[2] = __float22bfloat162_rn(make_float2(b[0], b[1]));
      u.h[3] = __float22bfloat162_rn(make_float2(b[2], b[3]));
      *(short8*)&ks[buf][r * LDK + c0 * 8] = u.s;
    }
    // V: pack (key 2kp, 2kp+1) per d -> one b32 per d at slot position
#pragma unroll
    for (int j = 0; j < 4; ++j) {
      *(unsigned*)&vs[buf][(cv * 8 + j) * 64 + (sk ^ (j << 3))] =
          pk2(vr[0][0][j], vr[1][0][j]);
      *(unsigned*)&vs[buf][(cv * 8 + 4 + j) * 64 + (sk ^ ((4 + j) << 3))] =
          pk2(vr[0][1][j], vr[1][1][j]);
    }
  };

  // ---- prologue: tile 0 ----
  stage_load(0);
  stage_write(0);

  int cur = 0;
  for (int kb = 0; kb < S; kb += BN) {
    __syncthreads();                       // buf[cur] ready for everyone
    const bool hn = (kb + BN) < S;
    if (hn) stage_load(kb + BN);           // latency hides under compute

    const short* ksc = ks[cur];
    const short* vsc = vs[cur];
    const int* msc = ms[cur];

    // ---- S^T = K Q^T (swapped, log2 domain), 32x32x16 ----
    // C: lane holds S[key = nt*32 + (r&3)+8*(r>>2)+4*hi][q = l5], r=0..15
    floatx16 sc[2];
#pragma unroll
    for (int nt = 0; nt < 2; ++nt)
#pragma unroll
      for (int r = 0; r < 16; ++r) sc[nt][r] = 0.f;
    __builtin_amdgcn_s_setprio(1);
#pragma unroll
    for (int nt = 0; nt < 2; ++nt)
#pragma unroll
      for (int kd = 0; kd < 4; ++kd) {
        short8 kf = *(const short8*)&ksc[(nt * 32 + l5) * LDK + kd * 16 + hi * 8];
        sc[nt] = __builtin_amdgcn_mfma_f32_32x32x16_bf16(kf, qf[kd], sc[nt], 0, 0, 0);
      }
    __builtin_amdgcn_s_setprio(0);

    // ---- no-max softmax: P = exp2(s2) (masked -> 0) ----
    // key(r) = nt*32 + 8*(r>>2) + 4*hi + (r&3)
    float s_el[2][4][4];
#pragma unroll
    for (int nt = 0; nt < 2; ++nt)
#pragma unroll
      for (int g = 0; g < 4; ++g) {
        int4 mm = *(const int4*)&msc[nt * 32 + 8 * g + 4 * hi];
        int mv[4] = {mm.x, mm.y, mm.z, mm.w};
#pragma unroll
        for (int c = 0; c < 4; ++c)
          s_el[nt][g][c] = mv[c] ? __builtin_exp2f(sc[nt][4 * g + c]) : 0.0f;
      }

    // ---- pack P: h[nt][g][m] = keys (nt*32+8g+4hi+2m, +1) as one bf16x2 ----
    unsigned h[2][4][2];
#pragma unroll
    for (int nt = 0; nt < 2; ++nt)
#pragma unroll
      for (int g = 0; g < 4; ++g) {
        h[nt][g][0] = pk2(s_el[nt][g][0], s_el[nt][g][1]);
        h[nt][g][1] = pk2(s_el[nt][g][2], s_el[nt][g][3]);
      }

    // ---- O += P V ; l += P 1 — P used directly as A-frag (slot order via
    // sigma-stored V); A slot (hi,j) of step st = key 16st + 8(j>>2)+4hi+(j&3)
    __builtin_amdgcn_s_setprio(1);
    const int vswz = (l5 & 7) << 3;
#pragma unroll
    for (int st = 0; st < 4; ++st) {
      const int nt = st >> 1, a2 = (st & 1) * 2;
      union { short8 s; unsigned u[4]; } af;
      af.u[0] = h[nt][a2][0];
      af.u[1] = h[nt][a2][1];
      af.u[2] = h[nt][a2 + 1][0];
      af.u[3] = h[nt][a2 + 1][1];
      accl = __builtin_amdgcn_mfma_f32_32x32x16_bf16(af.s, ones, accl, 0, 0, 0);
#pragma unroll
      for (int dn = 0; dn < 2; ++dn) {
        short8 bf = *(const short8*)&vsc[(dn * 32 + l5) * 64 +
                                         ((st * 16 + hi * 8) ^ vswz)];
        acc[dn] = __builtin_amdgcn_mfma_f32_32x32x16_bf16(af.s, bf, acc[dn], 0, 0, 0);
      }
    }
    __builtin_amdgcn_s_setprio(0);

    // write next tile into the other buffer AFTER compute (no barrier: other
    // waves only read buf[cur]; next iteration's sync publishes buf[cur^1])
    if (hn) stage_write(cur ^ 1);
    cur ^= 1;
  }

  // ---- epilogue: O /= l ; q(r) = base + (r&3) + 8*(r>>2) + 4*hi ----
#pragma unroll
  for (int r = 0; r < 16; ++r) {
    float inv = 1.0f / accl[r];
    int row = mblk * BM + wave * 32 + (r & 3) + 8 * (r >> 2) + 4 * hi;
    float* op = Out + (size_t)(bh * S + row) * D;
#pragma unroll
    for (int dn = 0; dn < 2; ++dn)
      op[dn * 32 + l5] = acc[dn][r] * inv;
  }
}

extern "C" void kernel_launch(void* const* d_in, const int* in_sizes, int n_in,
                              void* d_out, int out_size, void* d_ws, size_t ws_size,
                              hipStream_t stream) {
  const float* q = (const float*)d_in[0];
  const float* k = (const float*)d_in[1];
  const float* v = (const float*)d_in[2];
  const int* mask = (const int*)d_in[3];
  float* out = (float*)d_out;
  dim3 grid(S / BM, B * H);
  attn_flash_kernel<<<grid, dim3(256), 0, stream>>>(q, k, v, mask, out);
}

// Round 10
// 347.487 us; speedup vs baseline: 1.4599x; 1.4599x over previous
//
#include <hip/hip_runtime.h>
#include <hip/hip_bf16.h>

typedef __attribute__((ext_vector_type(8))) short short8;
typedef __attribute__((ext_vector_type(4))) float floatx4;

constexpr int B = 4, H = 16, S = 2048, D = 64;
constexpr int BM = 64;   // queries per workgroup (16 per wave)
constexpr int BN = 32;   // keys per main-loop iteration (small tile -> 6 blocks/CU)
constexpr int LDK = 72;  // K row stride: 64 d + pad (36 dwords -> bank rotation)
constexpr int LDV = 40;  // V row stride: 32 keys + pad (20 dwords, <=2-way banks)
constexpr int LDP = 40;  // P row stride: 32 keys + pad

// fold softmax scale and log2(e) into Q: exp(x*0.125) == exp2(x*0.125*log2e)
#define QSCALE (0.125f * 1.44269504088896f)

// 8 contiguous fp32 -> 8 bf16 via packed converts
__device__ __forceinline__ short8 ld8f_bf(const float* p, float sc) {
  floatx4 a = *(const floatx4*)p;
  floatx4 b = *(const floatx4*)(p + 4);
  union { short8 s; __hip_bfloat162 h[4]; } u;
  u.h[0] = __float22bfloat162_rn(make_float2(a[0] * sc, a[1] * sc));
  u.h[1] = __float22bfloat162_rn(make_float2(a[2] * sc, a[3] * sc));
  u.h[2] = __float22bfloat162_rn(make_float2(b[0] * sc, b[1] * sc));
  u.h[3] = __float22bfloat162_rn(make_float2(b[2] * sc, b[3] * sc));
  return u.s;
}

__device__ __forceinline__ unsigned pk2(float lo, float hi) {
  __hip_bfloat162 h = __float22bfloat162_rn(make_float2(lo, hi));
  return *reinterpret_cast<unsigned*>(&h);
}

__global__ __launch_bounds__(256, 6)
void attn_flash_kernel(const float* __restrict__ Q, const float* __restrict__ Kp,
                       const float* __restrict__ Vp, const int* __restrict__ Mask,
                       float* __restrict__ Out) {
  // Total LDS ~24.8 KB -> 6 blocks/CU (was 44.5 KB -> 3). Layouts are the
  // R6-verified ones, resized to BN=32 with pad-based (not XOR) bank spread.
  __shared__ __align__(16) short ks[2][BN * LDK];   // K [key][d]
  __shared__ __align__(16) short vs[2][D * LDV];    // V [d][key] (dword = key-pair)
  __shared__ __align__(16) short ps[4][16 * LDP];   // per-wave P [q][key]
  __shared__ __align__(16) int ms[2][BN];           // mask tile

  const int t = threadIdx.x;
  const int wave = t >> 6;
  const int lane = t & 63;
  const int quad = lane >> 4;
  const int lm = lane & 15;

  const int bh = blockIdx.y;
  const int bb = bh >> 4;
  const int mblk = blockIdx.x;

  const float* Qb = Q + (size_t)bh * S * D;
  const float* Kb = Kp + (size_t)bh * S * D;
  const float* Vb = Vp + (size_t)bh * S * D;
  const int* Mb = Mask + bb * S;

  // Q as MFMA B-operand (swapped QK^T): identical lane map as A usage.
  const int qrow = mblk * BM + wave * 16 + lm;
  const float* qp = Qb + (size_t)qrow * D;
  const short8 qf0 = ld8f_bf(qp + 0 * 32 + quad * 8, QSCALE);
  const short8 qf1 = ld8f_bf(qp + 1 * 32 + quad * 8, QSCALE);

  // all-ones B fragment: l row-sums via the matrix pipe
  short8 ones;
#pragma unroll
  for (int j = 0; j < 8; ++j) ones[j] = (short)0x3F80;  // bf16 1.0

  floatx4 acc[4], accl;
#pragma unroll
  for (int d = 0; d < 4; ++d) acc[d] = (floatx4){0.f, 0.f, 0.f, 0.f};
  accl = (floatx4){0.f, 0.f, 0.f, 0.f};

  // ---- staging geometry (each thread: 1 K row-chunk + 1 V key-pair chunk) ----
  const int r0 = t >> 3;          // K row 0..31
  const int c0 = t & 7;           // 8-elem d-chunk
  const int kp = t & 15;          // V key pair: keys 2kp, 2kp+1
  const int cv = t >> 4;          // V d-quad 0..15 (4 d values)
  const float* kg0 = Kb + (size_t)r0 * D + c0 * 8;
  const float* vg0 = Vb + (size_t)(2 * kp) * D + cv * 4;
  const float* vg1 = Vb + (size_t)(2 * kp + 1) * D + cv * 4;

  floatx4 kr0, kr1, vr0, vr1;   // staged next-tile fp32 (issue-early, write-late)
  int mreg = 0;

  auto stage_load = [&](int kb) {   // T14: issue global loads early
    const size_t off = (size_t)kb * D;
    kr0 = *(const floatx4*)(kg0 + off);
    kr1 = *(const floatx4*)(kg0 + off + 4);
    vr0 = *(const floatx4*)(vg0 + off);
    vr1 = *(const floatx4*)(vg1 + off);
    if (t < BN) mreg = Mb[kb + t];
  };

  auto stage_write = [&](int buf) {  // T14: convert + LDS write, late
    if (t < BN) ms[buf][t] = mreg;
    union { short8 s; __hip_bfloat162 h[4]; } u;
    u.h[0] = __float22bfloat162_rn(make_float2(kr0[0], kr0[1]));
    u.h[1] = __float22bfloat162_rn(make_float2(kr0[2], kr0[3]));
    u.h[2] = __float22bfloat162_rn(make_float2(kr1[0], kr1[1]));
    u.h[3] = __float22bfloat162_rn(make_float2(kr1[2], kr1[3]));
    *(short8*)&ks[buf][r0 * LDK + c0 * 8] = u.s;
    // V: pack (key 2kp, 2kp+1) per d -> one b32 per d, 4 total
#pragma unroll
    for (int j = 0; j < 4; ++j)
      *(unsigned*)&vs[buf][(cv * 4 + j) * LDV + 2 * kp] = pk2(vr0[j], vr1[j]);
  };

  // ---- prologue: tile 0 ----
  stage_load(0);
  stage_write(0);

  int cur = 0;
  for (int kb = 0; kb < S; kb += BN) {
    __syncthreads();                       // buf[cur] ready for everyone
    const bool hn = (kb + BN) < S;
    if (hn) stage_load(kb + BN);           // latency hides under compute

    const short* ksc = ks[cur];
    const short* vsc = vs[cur];
    const int* msc = ms[cur];

    // ---- S^T = K Q^T (swapped operands, log2 domain) ----
    // C: lane holds S[q=lm][key = nt*16 + quad*4 + r]
    floatx4 sc[2];
    __builtin_amdgcn_s_setprio(1);
#pragma unroll
    for (int nt = 0; nt < 2; ++nt) {
      short8 kf0 = *(const short8*)&ksc[(nt * 16 + lm) * LDK + 0 * 32 + quad * 8];
      short8 kf1 = *(const short8*)&ksc[(nt * 16 + lm) * LDK + 1 * 32 + quad * 8];
      floatx4 z = (floatx4){0.f, 0.f, 0.f, 0.f};
      z = __builtin_amdgcn_mfma_f32_16x16x32_bf16(kf0, qf0, z, 0, 0, 0);
      z = __builtin_amdgcn_mfma_f32_16x16x32_bf16(kf1, qf1, z, 0, 0, 0);
      sc[nt] = z;
    }
    __builtin_amdgcn_s_setprio(0);

    // ---- softmax + pack + P-write (key = nt*16 + quad*4 + r at q=lm) ----
    short* pw = &ps[wave][0];
#pragma unroll
    for (int nt = 0; nt < 2; ++nt) {
      int4 mm = *(const int4*)&msc[nt * 16 + quad * 4];
      int mv[4] = {mm.x, mm.y, mm.z, mm.w};
      float s0 = mv[0] ? __builtin_exp2f(sc[nt][0]) : 0.0f;
      float s1 = mv[1] ? __builtin_exp2f(sc[nt][1]) : 0.0f;
      float s2 = mv[2] ? __builtin_exp2f(sc[nt][2]) : 0.0f;
      float s3 = mv[3] ? __builtin_exp2f(sc[nt][3]) : 0.0f;
      uint2 pp = make_uint2(pk2(s0, s1), pk2(s2, s3));
      *(uint2*)&pw[lm * LDP + nt * 16 + quad * 4] = pp;
    }

    // ---- O += P V ; l += P 1 (same-wave lgkmcnt orders ps write->read) ----
    __builtin_amdgcn_s_setprio(1);
    short8 af = *(const short8*)&pw[lm * LDP + quad * 8];
    accl = __builtin_amdgcn_mfma_f32_16x16x32_bf16(af, ones, accl, 0, 0, 0);
#pragma unroll
    for (int dn = 0; dn < 4; ++dn) {
      short8 bf = *(const short8*)&vsc[(dn * 16 + lm) * LDV + quad * 8];
      acc[dn] = __builtin_amdgcn_mfma_f32_16x16x32_bf16(af, bf, acc[dn], 0, 0, 0);
    }
    __builtin_amdgcn_s_setprio(0);

    // write next tile into the other buffer AFTER compute (no barrier: other
    // waves only read buf[cur]; next iteration's sync publishes buf[cur^1])
    if (hn) stage_write(cur ^ 1);
    cur ^= 1;
  }

  // ---- epilogue: O /= l ----
#pragma unroll
  for (int r = 0; r < 4; ++r) {
    float inv = 1.0f / accl[r];
    int row = mblk * BM + wave * 16 + quad * 4 + r;
    float* op = Out + (size_t)(bh * S + row) * D;
#pragma unroll
    for (int dn = 0; dn < 4; ++dn)
      op[dn * 16 + lm] = acc[dn][r] * inv;
  }
}

extern "C" void kernel_launch(void* const* d_in, const int* in_sizes, int n_in,
                              void* d_out, int out_size, void* d_ws, size_t ws_size,
                              hipStream_t stream) {
  const float* q = (const float*)d_in[0];
  const float* k = (const float*)d_in[1];
  const float* v = (const float*)d_in[2];
  const int* mask = (const int*)d_in[3];
  float* out = (float*)d_out;
  dim3 grid(S / BM, B * H);
  attn_flash_kernel<<<grid, dim3(256), 0, stream>>>(q, k, v, mask, out);
}

// Round 13
// 293.329 us; speedup vs baseline: 1.7295x; 1.1846x over previous
//
#include <hip/hip_runtime.h>
#include <hip/hip_bf16.h>

typedef __attribute__((ext_vector_type(8))) short short8;
typedef __attribute__((ext_vector_type(4))) float floatx4;

constexpr int B = 4, H = 16, S = 2048, D = 64;
constexpr int BM = 64;   // queries per workgroup (16 per wave)
constexpr int BN = 64;   // keys per main-loop iteration
constexpr int LDK = 72;  // K row stride (bf16): 36 dwords/row -> bank rotation
constexpr int LDP = 72;  // P row stride (bf16)
constexpr int NT = S / BN;  // 32 K-tiles

// fold softmax scale and log2(e) into Q: exp(x*0.125) == exp2(x*0.125*log2e)
#define QSCALE (0.125f * 1.44269504088896f)

// 8 contiguous fp32 -> 8 bf16 via packed converts
__device__ __forceinline__ short8 ld8f_bf(const float* p, float sc) {
  floatx4 a = *(const floatx4*)p;
  floatx4 b = *(const floatx4*)(p + 4);
  union { short8 s; __hip_bfloat162 h[4]; } u;
  u.h[0] = __float22bfloat162_rn(make_float2(a[0] * sc, a[1] * sc));
  u.h[1] = __float22bfloat162_rn(make_float2(a[2] * sc, a[3] * sc));
  u.h[2] = __float22bfloat162_rn(make_float2(b[0] * sc, b[1] * sc));
  u.h[3] = __float22bfloat162_rn(make_float2(b[2] * sc, b[3] * sc));
  return u.s;
}

__device__ __forceinline__ unsigned pk2(float lo, float hi) {
  __hip_bfloat162 h = __float22bfloat162_rn(make_float2(lo, hi));
  return *reinterpret_cast<unsigned*>(&h);
}

// barrier WITHOUT vmcnt drain: publish own LDS writes, sync, leave global
// loads in flight (T4 counted-vmcnt happens at the register uses).
__device__ __forceinline__ void wg_barrier() {
  asm volatile("s_waitcnt lgkmcnt(0)" ::: "memory");
  __builtin_amdgcn_s_barrier();
}

__global__ __launch_bounds__(256, 2)
void attn_flash_kernel(const float* __restrict__ Q, const float* __restrict__ Kp,
                       const float* __restrict__ Vp, const int* __restrict__ Mask,
                       float* __restrict__ Out) {
  // R6-verified layouts: K [key][d] stride 72; V [d][key ^ ((d&7)<<3)]
  // (dword = key-pair); ps per-wave [q][key] stride 72.
  __shared__ __align__(16) short ks[2][BN * LDK];
  __shared__ __align__(16) short vs[2][D * 64];
  __shared__ __align__(16) short ps[4][16 * LDP];
  __shared__ __align__(16) int ms[2][BN];

  const int t = threadIdx.x;
  const int wave = t >> 6;
  const int lane = t & 63;
  const int quad = lane >> 4;
  const int lm = lane & 15;

  const int bh = blockIdx.y;
  const int bb = bh >> 4;
  const int mblk = blockIdx.x;

  const float* Qb = Q + (size_t)bh * S * D;
  const float* Kb = Kp + (size_t)bh * S * D;
  const float* Vb = Vp + (size_t)bh * S * D;
  const int* Mb = Mask + bb * S;

  // Q as MFMA B-operand (swapped QK^T)
  const int qrow = mblk * BM + wave * 16 + lm;
  const float* qp = Qb + (size_t)qrow * D;
  const short8 qf0 = ld8f_bf(qp + 0 * 32 + quad * 8, QSCALE);
  const short8 qf1 = ld8f_bf(qp + 1 * 32 + quad * 8, QSCALE);

  short8 ones;
#pragma unroll
  for (int j = 0; j < 8; ++j) ones[j] = (short)0x3F80;  // bf16 1.0

  floatx4 acc[4], accl;
#pragma unroll
  for (int d = 0; d < 4; ++d) acc[d] = (floatx4){0.f, 0.f, 0.f, 0.f};
  accl = (floatx4){0.f, 0.f, 0.f, 0.f};

  // ---- staging geometry ----
  const int r0 = t >> 3;          // K row 0..31 (and +32)
  const int c0 = t & 7;
  const int r1 = r0 + 32;
  const int kp = t & 31;          // V key pair: keys 2kp, 2kp+1
  const int cv = t >> 5;          // V d-chunk 0..7
  const float* kg0 = Kb + (size_t)r0 * D + c0 * 8;
  const float* kg1 = Kb + (size_t)r1 * D + c0 * 8;
  const float* vg0 = Vb + (size_t)(2 * kp) * D + cv * 8;
  const float* vg1 = Vb + (size_t)(2 * kp + 1) * D + cv * 8;
  const int k2 = 2 * kp;

  // two independent staging register sets (depth-2 pipeline), named statically
  floatx4 kA00, kA01, kA10, kA11, vA00, vA01, vA10, vA11; int mA;
  floatx4 kB00, kB01, kB10, kB11, vB00, vB01, vB10, vB11; int mB;

#define STAGE_LOAD(kb, S_) do {                                             \
    const size_t off_ = (size_t)(kb) * D;                                   \
    k##S_##00 = *(const floatx4*)(kg0 + off_);                              \
    k##S_##01 = *(const floatx4*)(kg0 + off_ + 4);                          \
    k##S_##10 = *(const floatx4*)(kg1 + off_);                              \
    k##S_##11 = *(const floatx4*)(kg1 + off_ + 4);                          \
    v##S_##00 = *(const floatx4*)(vg0 + off_);                              \
    v##S_##01 = *(const floatx4*)(vg0 + off_ + 4);                          \
    v##S_##10 = *(const floatx4*)(vg1 + off_);                              \
    v##S_##11 = *(const floatx4*)(vg1 + off_ + 4);                          \
    m##S_ = Mb[(kb) + (t & 63)];                                            \
  } while (0)

#define STAGE_WRITE(buf, S_) do {                                           \
    if (t < BN) ms[buf][t] = m##S_;                                         \
    {                                                                       \
      union { short8 s; __hip_bfloat162 h[4]; } u_;                         \
      u_.h[0] = __float22bfloat162_rn(make_float2(k##S_##00[0], k##S_##00[1])); \
      u_.h[1] = __float22bfloat162_rn(make_float2(k##S_##00[2], k##S_##00[3])); \
      u_.h[2] = __float22bfloat162_rn(make_float2(k##S_##01[0], k##S_##01[1])); \
      u_.h[3] = __float22bfloat162_rn(make_float2(k##S_##01[2], k##S_##01[3])); \
      *(short8*)&ks[buf][r0 * LDK + c0 * 8] = u_.s;                         \
      u_.h[0] = __float22bfloat162_rn(make_float2(k##S_##10[0], k##S_##10[1])); \
      u_.h[1] = __float22bfloat162_rn(make_float2(k##S_##10[2], k##S_##10[3])); \
      u_.h[2] = __float22bfloat162_rn(make_float2(k##S_##11[0], k##S_##11[1])); \
      u_.h[3] = __float22bfloat162_rn(make_float2(k##S_##11[2], k##S_##11[3])); \
      *(short8*)&ks[buf][r1 * LDK + c0 * 8] = u_.s;                         \
    }                                                                       \
    _Pragma("unroll")                                                       \
    for (int j = 0; j < 4; ++j) {                                           \
      *(unsigned*)&vs[buf][(cv * 8 + j) * 64 + (k2 ^ (j << 3))] =           \
          pk2(v##S_##00[j], v##S_##10[j]);                                  \
      *(unsigned*)&vs[buf][(cv * 8 + 4 + j) * 64 + (k2 ^ ((4 + j) << 3))] = \
          pk2(v##S_##01[j], v##S_##11[j]);                                  \
    }                                                                       \
  } while (0)

  short* pw = &ps[wave][0];
  const int vswz = (lm & 7) << 3;

  auto compute = [&](const short* ksc, const short* vsc, const int* msc) {
    // ---- S^T = K Q^T (swapped operands, log2 domain) ----
    floatx4 sc[4];
    __builtin_amdgcn_s_setprio(1);
#pragma unroll
    for (int nt = 0; nt < 4; ++nt) {
      short8 kf0 = *(const short8*)&ksc[(nt * 16 + lm) * LDK + 0 * 32 + quad * 8];
      short8 kf1 = *(const short8*)&ksc[(nt * 16 + lm) * LDK + 1 * 32 + quad * 8];
      floatx4 z = (floatx4){0.f, 0.f, 0.f, 0.f};
      z = __builtin_amdgcn_mfma_f32_16x16x32_bf16(kf0, qf0, z, 0, 0, 0);
      z = __builtin_amdgcn_mfma_f32_16x16x32_bf16(kf1, qf1, z, 0, 0, 0);
      sc[nt] = z;
    }
    __builtin_amdgcn_s_setprio(0);

    // ---- no-max softmax + pack + P-write (key = nt*16 + quad*4 + r, q=lm) ----
#pragma unroll
    for (int nt = 0; nt < 4; ++nt) {
      int4 mm = *(const int4*)&msc[nt * 16 + quad * 4];
      int mv[4] = {mm.x, mm.y, mm.z, mm.w};
      float s0 = mv[0] ? __builtin_exp2f(sc[nt][0]) : 0.0f;
      float s1 = mv[1] ? __builtin_exp2f(sc[nt][1]) : 0.0f;
      float s2 = mv[2] ? __builtin_exp2f(sc[nt][2]) : 0.0f;
      float s3 = mv[3] ? __builtin_exp2f(sc[nt][3]) : 0.0f;
      uint2 pp = make_uint2(pk2(s0, s1), pk2(s2, s3));
      *(uint2*)&pw[lm * LDP + nt * 16 + quad * 4] = pp;
    }

    // ---- O += P V ; l += P 1 (same-wave lgkmcnt orders ps write->read) ----
    __builtin_amdgcn_s_setprio(1);
#pragma unroll
    for (int kt = 0; kt < 2; ++kt) {
      short8 af = *(const short8*)&pw[lm * LDP + kt * 32 + quad * 8];
      accl = __builtin_amdgcn_mfma_f32_16x16x32_bf16(af, ones, accl, 0, 0, 0);
#pragma unroll
      for (int dn = 0; dn < 4; ++dn) {
        short8 bf = *(const short8*)&vsc[(dn * 16 + lm) * 64 +
                                         ((kt * 32 + quad * 8) ^ vswz)];
        acc[dn] = __builtin_amdgcn_mfma_f32_16x16x32_bf16(af, bf, acc[dn], 0, 0, 0);
      }
    }
    __builtin_amdgcn_s_setprio(0);
  };

  // ---- prologue: tile 0 staged, tile 1 in A-regs ----
  STAGE_LOAD(0, A);
  STAGE_WRITE(0, A);      // compiler waits vmcnt for A's loads here only
  STAGE_LOAD(BN, A);      // tile 1

  // even tiles always live in buf0, odd tiles in buf1 -> fully static indexing
#pragma unroll 1
  for (int tt = 0; tt < NT; tt += 2) {
    // -------- even tile tt (buf0); A holds tile tt+1; issue B <- tt+2 ------
    wg_barrier();
    if (tt + 2 < NT) STAGE_LOAD((tt + 2) * BN, B);
    compute(ks[0], vs[0], ms[0]);
    STAGE_WRITE(1, A);                       // tile tt+1 -> buf1
    // -------- odd tile tt+1 (buf1); B holds tile tt+2; issue A <- tt+3 ----
    wg_barrier();
    if (tt + 3 < NT) STAGE_LOAD((tt + 3) * BN, A);
    compute(ks[1], vs[1], ms[1]);
    if (tt + 2 < NT) STAGE_WRITE(0, B);      // tile tt+2 -> buf0
  }

  // ---- epilogue: O /= l ----
#pragma unroll
  for (int r = 0; r < 4; ++r) {
    float inv = 1.0f / accl[r];
    int row = mblk * BM + wave * 16 + quad * 4 + r;
    float* op = Out + (size_t)(bh * S + row) * D;
#pragma unroll
    for (int dn = 0; dn < 4; ++dn)
      op[dn * 16 + lm] = acc[dn][r] * inv;
  }
}

extern "C" void kernel_launch(void* const* d_in, const int* in_sizes, int n_in,
                              void* d_out, int out_size, void* d_ws, size_t ws_size,
                              hipStream_t stream) {
  const float* q = (const float*)d_in[0];
  const float* k = (const float*)d_in[1];
  const float* v = (const float*)d_in[2];
  const int* mask = (const int*)d_in[3];
  float* out = (float*)d_out;
  dim3 grid(S / BM, B * H);
  attn_flash_kernel<<<grid, dim3(256), 0, stream>>>(q, k, v, mask, out);
}